// Round 1
// baseline (292.897 us; speedup 1.0000x reference)
//
#include <hip/hip_runtime.h>
#include <hip/hip_bf16.h>

typedef unsigned short u16;

#define D_KEY   128
#define BANK_N  9720
#define BANK_P  9728   /* 76*128 */
#define N_TOK   1620
#define N_PAD   1664   /* 13*128 */
#define OBJ_N   3
#define M_ROWS  1539   /* 3*512 + 3 mask rows */
#define M_PAD   1664
#define LDCOL   1664
#define QK_SCALE 0.08838834764831845f

typedef __bf16 bf16x8 __attribute__((ext_vector_type(8)));
typedef float  f32x4  __attribute__((ext_vector_type(4)));

__device__ __forceinline__ float bf2f(u16 u) {
  union { unsigned int i; float f; } v; v.i = ((unsigned int)u) << 16; return v.f;
}
__device__ __forceinline__ u16 f2bf(float f) {
  unsigned int x = __float_as_uint(f);
  unsigned int r = x + 0x7fffu + ((x >> 16) & 1u);  // RNE
  return (u16)(r >> 16);
}

__device__ __forceinline__ void load_lds16(const void* g, void* l) {
  __builtin_amdgcn_global_load_lds(
      (const __attribute__((address_space(1))) void*)g,
      (__attribute__((address_space(3))) void*)l, 16, 0, 0);
}

// ---------------- cast kernels ----------------
__global__ void cast_qT(const float* __restrict__ q, u16* __restrict__ qT) {
  int idx = blockIdx.x * 256 + threadIdx.x;          // N_PAD*128
  if (idx >= N_PAD * D_KEY) return;
  int n = idx >> 7, d = idx & 127;
  float v = (n < N_TOK) ? q[d * N_TOK + n] * QK_SCALE : 0.f;
  qT[idx] = f2bf(v);
}

__global__ void cast_keysT(const float* __restrict__ keys, u16* __restrict__ kT) {
  int idx = blockIdx.x * 256 + threadIdx.x;          // BANK_P*128
  if (idx >= BANK_P * D_KEY) return;
  int k = idx >> 7, d = idx & 127;
  float v = (k < BANK_N) ? keys[d * BANK_N + k] : 0.f;
  kT[idx] = f2bf(v);
}

__global__ void cast_vm(const float* __restrict__ values, const float* __restrict__ masks,
                        u16* __restrict__ vm) {
  int idx = blockIdx.x * 256 + threadIdx.x;          // M_PAD*BANK_P
  if (idx >= M_PAD * BANK_P) return;
  int m = idx / BANK_P;
  int k = idx - m * BANK_P;
  float v = 0.f;
  if (k < BANK_N) {
    if (m < 1536)        v = values[(size_t)m * BANK_N + k];
    else if (m < M_ROWS) v = masks[(size_t)(m - 1536) * BANK_N + k];
  }
  vm[idx] = f2bf(v);
}

// ---------------- GEMM: C[M][N] = A[M][K] * B[N][K]^T (bf16 in, fp32 acc) ----------------
// 128x128 block tile, BK=32, 256 threads (4 waves, 2x2), 4x4 MFMA subtiles/wave.
template<bool STORE_BF16>
__global__ void gemm_bt(const u16* __restrict__ A, const u16* __restrict__ B,
                        void* __restrict__ Cv, int lda, int ldb, int ldc,
                        int kChunk, size_t cPartStride)
{
  __shared__ __align__(16) u16 As[128 * 32];
  __shared__ __align__(16) u16 Bs[128 * 32];

  const int tid  = threadIdx.x;
  const int wave = tid >> 6;
  const int lane = tid & 63;
  const int bn = blockIdx.x, bm = blockIdx.y, bz = blockIdx.z;

  const int kbeg = bz * kChunk;
  const int kend = kbeg + kChunk;

  const u16* Abase = A + (size_t)bm * 128 * lda;
  const u16* Bbase = B + (size_t)bn * 128 * ldb;

  const int r  = lane >> 2;          // 0..15 row within 16-row segment
  const int c8 = (lane & 3) << 3;    // 0,8,16,24 col (bf16 elems)
  const int s0 = wave, s1 = wave + 4;

  f32x4 acc[4][4];
#pragma unroll
  for (int i = 0; i < 4; i++)
#pragma unroll
    for (int j = 0; j < 4; j++) acc[i][j] = (f32x4){0.f, 0.f, 0.f, 0.f};

  const int m_in = lane & 15;
  const int quad = lane >> 4;
  const int wm = (wave >> 1) * 64;
  const int wn = (wave & 1) * 64;

  for (int kt = kbeg; kt < kend; kt += 32) {
    // stage 128x32 A-tile and B-tile; each wave: 2 16-row segments of each
    load_lds16(Abase + (size_t)(s0 * 16 + r) * lda + kt + c8, &As[s0 * 512]);
    load_lds16(Abase + (size_t)(s1 * 16 + r) * lda + kt + c8, &As[s1 * 512]);
    load_lds16(Bbase + (size_t)(s0 * 16 + r) * ldb + kt + c8, &Bs[s0 * 512]);
    load_lds16(Bbase + (size_t)(s1 * 16 + r) * ldb + kt + c8, &Bs[s1 * 512]);
    __syncthreads();

    bf16x8 af[4], bfr[4];
#pragma unroll
    for (int i = 0; i < 4; i++)
      af[i] = *(const bf16x8*)&As[(wm + i * 16 + m_in) * 32 + quad * 8];
#pragma unroll
    for (int j = 0; j < 4; j++)
      bfr[j] = *(const bf16x8*)&Bs[(wn + j * 16 + m_in) * 32 + quad * 8];
#pragma unroll
    for (int i = 0; i < 4; i++)
#pragma unroll
      for (int j = 0; j < 4; j++)
        acc[i][j] = __builtin_amdgcn_mfma_f32_16x16x32_bf16(af[i], bfr[j], acc[i][j], 0, 0, 0);
    __syncthreads();
  }

  // epilogue: D layout col=lane&15, row=quad*4+t  [verified m89]
  if (STORE_BF16) {
    u16* C = (u16*)Cv;
#pragma unroll
    for (int i = 0; i < 4; i++)
#pragma unroll
      for (int j = 0; j < 4; j++)
#pragma unroll
        for (int t = 0; t < 4; t++) {
          int row = bm * 128 + wm + i * 16 + quad * 4 + t;
          int col = bn * 128 + wn + j * 16 + m_in;
          C[(size_t)row * ldc + col] = f2bf(acc[i][j][t]);
        }
  } else {
    float* C = (float*)Cv + (size_t)bz * cPartStride;
#pragma unroll
    for (int i = 0; i < 4; i++)
#pragma unroll
      for (int j = 0; j < 4; j++)
#pragma unroll
        for (int t = 0; t < 4; t++) {
          int row = bm * 128 + wm + i * 16 + quad * 4 + t;
          int col = bn * 128 + wn + j * 16 + m_in;
          C[(size_t)row * ldc + col] = acc[i][j][t];
        }
  }
}

// ---------------- softmax over k (row-wise on P[n][k]) ----------------
__global__ void softmax_rows(u16* __restrict__ P) {
  __shared__ __align__(16) u16 row[BANK_P];   // 19456 B
  __shared__ float red[8];
  const int n = blockIdx.x;                   // 0..N_TOK-1
  const int tid = threadIdx.x;
  u16* prow = P + (size_t)n * BANK_P;

  for (int k = tid; k < BANK_N; k += 256) row[k] = prow[k];
  __syncthreads();

  float m = -1e30f;
  for (int k = tid; k < BANK_N; k += 256) m = fmaxf(m, bf2f(row[k]));
#pragma unroll
  for (int o = 32; o; o >>= 1) m = fmaxf(m, __shfl_xor(m, o));
  if ((tid & 63) == 0) red[tid >> 6] = m;
  __syncthreads();
  m = fmaxf(fmaxf(red[0], red[1]), fmaxf(red[2], red[3]));

  float s = 0.f;
  for (int k = tid; k < BANK_N; k += 256) s += __expf(bf2f(row[k]) - m);
#pragma unroll
  for (int o = 32; o; o >>= 1) s += __shfl_xor(s, o);
  if ((tid & 63) == 0) red[4 + (tid >> 6)] = s;
  __syncthreads();
  const float inv = 1.f / (red[4] + red[5] + red[6] + red[7]);

  for (int k = tid; k < BANK_N; k += 256)
    prow[k] = f2bf(__expf(bf2f(row[k]) - m) * inv);
}

// ---------------- epilogue ----------------
__global__ void epilogue(const float* __restrict__ memC, const float* __restrict__ q_out,
                         float* __restrict__ out, int nParts) {
  int idx = blockIdx.x * 256 + threadIdx.x;
  if (idx >= OBJ_N * 1024 * N_TOK) return;
  int n = idx % N_TOK;
  int t = idx / N_TOK;
  int c = t & 1023;
  int o = t >> 10;
  const size_t ps = (size_t)M_PAD * LDCOL;
  float v;
  if (c < 512) {
    size_t off = (size_t)(o * 512 + c) * LDCOL + n;
    v = 0.f;
    for (int z = 0; z < nParts; z++) v += memC[z * ps + off];
  } else {
    size_t offm = (size_t)(1536 + o) * LDCOL + n;
    float mm = 0.f;
    for (int z = 0; z < nParts; z++) mm += memC[z * ps + offm];
    v = q_out[(size_t)(o * 512 + (c - 512)) * N_TOK + n] * mm;
  }
  out[idx] = v;
}

extern "C" void kernel_launch(void* const* d_in, const int* in_sizes, int n_in,
                              void* d_out, int out_size, void* d_ws, size_t ws_size,
                              hipStream_t stream) {
  const float* keys   = (const float*)d_in[0];
  const float* q_in   = (const float*)d_in[1];
  const float* q_out  = (const float*)d_in[2];
  const float* values = (const float*)d_in[3];
  const float* masks  = (const float*)d_in[4];
  float* out = (float*)d_out;

  char* ws = (char*)d_ws;
  size_t off = 0;
  auto alloc = [&](size_t bytes) -> void* {
    void* p = ws + off; off += (bytes + 255) & ~(size_t)255; return p;
  };
  u16* qT = (u16*)alloc((size_t)N_PAD * D_KEY * 2);
  u16* kT = (u16*)alloc((size_t)BANK_P * D_KEY * 2);
  u16* vm = (u16*)alloc((size_t)M_PAD * BANK_P * 2);
  u16* P  = (u16*)alloc((size_t)N_PAD * BANK_P * 2);

  int nParts = 4;
  while (nParts > 1 && off + (size_t)nParts * M_PAD * LDCOL * 4 > ws_size) nParts >>= 1;
  float* memC = (float*)alloc((size_t)nParts * M_PAD * LDCOL * 4);

  cast_qT<<<(N_PAD * D_KEY + 255) / 256, 256, 0, stream>>>(q_in, qT);
  cast_keysT<<<(BANK_P * D_KEY + 255) / 256, 256, 0, stream>>>(keys, kT);
  cast_vm<<<(M_PAD * BANK_P + 255) / 256, 256, 0, stream>>>(values, masks, vm);

  // QK^T: St[n][k] = qT[n][:] . keysT[k][:]   (M=N_PAD, N=BANK_P, K=128)
  gemm_bt<true><<<dim3(BANK_P / 128, N_PAD / 128, 1), 256, 0, stream>>>(
      qT, kT, (void*)P, D_KEY, D_KEY, BANK_P, D_KEY, 0);

  softmax_rows<<<N_TOK, 256, 0, stream>>>(P);

  // mem: C[m][n] = vm[m][:] . P[n][:]   (M=M_PAD, N=N_PAD, K=BANK_P), split-K
  int kChunk = BANK_P / nParts;
  gemm_bt<false><<<dim3(N_PAD / 128, M_PAD / 128, nParts), 256, 0, stream>>>(
      vm, P, (void*)memC, BANK_P, BANK_P, LDCOL, kChunk, (size_t)M_PAD * LDCOL);

  epilogue<<<(OBJ_N * 1024 * N_TOK + 255) / 256, 256, 0, stream>>>(memC, q_out, out, nParts);
}

// Round 2
// 279.150 us; speedup vs baseline: 1.0492x; 1.0492x over previous
//
#include <hip/hip_runtime.h>
#include <hip/hip_bf16.h>

typedef unsigned short u16;

#define D_KEY   128
#define BANK_N  9720
#define BANK_P  9728   /* 76*128 */
#define N_TOK   1620
#define N_PAD   1664   /* 13*128 */
#define OBJ_N   3
#define M_ROWS  1539   /* 3*512 + 3 mask rows */
#define M_PAD   1664
#define LDCOL   1664
#define QK_SCALE 0.08838834764831845f

typedef __bf16 bf16x8 __attribute__((ext_vector_type(8)));
typedef float  f32x4  __attribute__((ext_vector_type(4)));

__device__ __forceinline__ float bf2f(u16 u) {
  union { unsigned int i; float f; } v; v.i = ((unsigned int)u) << 16; return v.f;
}
__device__ __forceinline__ u16 f2bf(float f) {
  unsigned int x = __float_as_uint(f);
  unsigned int r = x + 0x7fffu + ((x >> 16) & 1u);  // RNE
  return (u16)(r >> 16);
}

__device__ __forceinline__ void load_lds16(const void* g, void* l) {
  __builtin_amdgcn_global_load_lds(
      (const __attribute__((address_space(1))) void*)g,
      (__attribute__((address_space(3))) void*)l, 16, 0, 0);
}

// ---------------- cast kernels ----------------
__global__ void cast_qT(const float* __restrict__ q, u16* __restrict__ qT) {
  int idx = blockIdx.x * 256 + threadIdx.x;          // N_PAD*128
  if (idx >= N_PAD * D_KEY) return;
  int n = idx >> 7, d = idx & 127;
  float v = (n < N_TOK) ? q[d * N_TOK + n] * QK_SCALE : 0.f;
  qT[idx] = f2bf(v);
}

// LDS-tiled transpose: keys[d][bank] (fp32) -> kT[bank][d] (bf16), coalesced both sides
__global__ void transpose_keys(const float* __restrict__ keys, u16* __restrict__ kT) {
  __shared__ float t[64][65];
  const int bk = blockIdx.x * 64;       // bank base
  const int bd = blockIdx.y * 64;       // d base
  const int tx = threadIdx.x & 63;
  const int ty = threadIdx.x >> 6;      // 0..3
#pragma unroll
  for (int i = 0; i < 64; i += 4) {
    int d = bd + ty + i;
    int k = bk + tx;
    t[ty + i][tx] = (k < BANK_N) ? keys[(size_t)d * BANK_N + k] : 0.f;
  }
  __syncthreads();
#pragma unroll
  for (int i = 0; i < 64; i += 4) {
    int r = ty + i;                      // bank offset within tile
    kT[(size_t)(bk + r) * D_KEY + bd + tx] = f2bf(t[tx][r]);
  }
}

__global__ void cast_vm(const float* __restrict__ values, const float* __restrict__ masks,
                        u16* __restrict__ vm) {
  const int NV = BANK_P / 4;                          // 2432 vec4 per row
  int idx = blockIdx.x * 256 + threadIdx.x;
  if (idx >= M_PAD * NV) return;
  int m = idx / NV;
  int k4 = (idx - m * NV) * 4;
  float4 v = make_float4(0.f, 0.f, 0.f, 0.f);
  const float* src = nullptr;
  if (m < 1536)        src = values + (size_t)m * BANK_N;
  else if (m < M_ROWS) src = masks + (size_t)(m - 1536) * BANK_N;
  if (src) {
    if (k4 + 3 < BANK_N) v = *(const float4*)(src + k4);
    else {
      if (k4     < BANK_N) v.x = src[k4];
      if (k4 + 1 < BANK_N) v.y = src[k4 + 1];
      if (k4 + 2 < BANK_N) v.z = src[k4 + 2];
      if (k4 + 3 < BANK_N) v.w = src[k4 + 3];
    }
  }
  ushort4 o;
  o.x = f2bf(v.x); o.y = f2bf(v.y); o.z = f2bf(v.z); o.w = f2bf(v.w);
  *(ushort4*)(vm + (size_t)m * BANK_P + k4) = o;
}

// ---------------- GEMM: C[M][N] = A[M][K] * B[N][K]^T (bf16 in, fp32 acc) ----------------
// 128x128 block tile, BK=32, 256 threads (4 waves, 2x2), 4x4 MFMA subtiles/wave.
// SWZ: 1D grid of 169*nParts blocks, grouped-launch decode (G=4 bn columns, bz slowest)
template<bool STORE_BF16, bool SWZ>
__global__ void gemm_bt(const u16* __restrict__ A, const u16* __restrict__ B,
                        void* __restrict__ Cv, int lda, int ldb, int ldc,
                        int kChunk, size_t cPartStride)
{
  __shared__ __align__(16) u16 As[128 * 32];
  __shared__ __align__(16) u16 Bs[128 * 32];

  const int tid  = threadIdx.x;
  const int wave = tid >> 6;
  const int lane = tid & 63;

  int bn, bm, bz;
  if (SWZ) {
    int b = blockIdx.x;
    bz = b / 169;
    int r = b - bz * 169;
    int gid = r / 52;                 // 4 groups of bn columns: {0-3},{4-7},{8-11},{12}
    int rem = r - gid * 52;
    int width = (gid < 3) ? 4 : 1;
    bm = rem / width;
    bn = gid * 4 + (rem - bm * width);
  } else {
    bn = blockIdx.x; bm = blockIdx.y; bz = blockIdx.z;
  }

  const int kbeg = bz * kChunk;
  const int kend = kbeg + kChunk;

  const u16* Abase = A + (size_t)bm * 128 * lda;
  const u16* Bbase = B + (size_t)bn * 128 * ldb;

  const int r  = lane >> 2;          // 0..15 row within 16-row segment
  const int c8 = (lane & 3) << 3;    // 0,8,16,24 col (bf16 elems)
  const int s0 = wave, s1 = wave + 4;

  f32x4 acc[4][4];
#pragma unroll
  for (int i = 0; i < 4; i++)
#pragma unroll
    for (int j = 0; j < 4; j++) acc[i][j] = (f32x4){0.f, 0.f, 0.f, 0.f};

  const int m_in = lane & 15;
  const int quad = lane >> 4;
  const int wm = (wave >> 1) * 64;
  const int wn = (wave & 1) * 64;

  for (int kt = kbeg; kt < kend; kt += 32) {
    load_lds16(Abase + (size_t)(s0 * 16 + r) * lda + kt + c8, &As[s0 * 512]);
    load_lds16(Abase + (size_t)(s1 * 16 + r) * lda + kt + c8, &As[s1 * 512]);
    load_lds16(Bbase + (size_t)(s0 * 16 + r) * ldb + kt + c8, &Bs[s0 * 512]);
    load_lds16(Bbase + (size_t)(s1 * 16 + r) * ldb + kt + c8, &Bs[s1 * 512]);
    __syncthreads();

    bf16x8 af[4], bfr[4];
#pragma unroll
    for (int i = 0; i < 4; i++)
      af[i] = *(const bf16x8*)&As[(wm + i * 16 + m_in) * 32 + quad * 8];
#pragma unroll
    for (int j = 0; j < 4; j++)
      bfr[j] = *(const bf16x8*)&Bs[(wn + j * 16 + m_in) * 32 + quad * 8];
#pragma unroll
    for (int i = 0; i < 4; i++)
#pragma unroll
      for (int j = 0; j < 4; j++)
        acc[i][j] = __builtin_amdgcn_mfma_f32_16x16x32_bf16(af[i], bfr[j], acc[i][j], 0, 0, 0);
    __syncthreads();
  }

  // epilogue: D layout col=lane&15, row=quad*4+t  [verified m89]
  if (STORE_BF16) {
    u16* C = (u16*)Cv;
#pragma unroll
    for (int i = 0; i < 4; i++)
#pragma unroll
      for (int j = 0; j < 4; j++)
#pragma unroll
        for (int t = 0; t < 4; t++) {
          int row = bm * 128 + wm + i * 16 + quad * 4 + t;
          int col = bn * 128 + wn + j * 16 + m_in;
          C[(size_t)row * ldc + col] = f2bf(acc[i][j][t]);
        }
  } else {
    float* C = (float*)Cv + (size_t)bz * cPartStride;
#pragma unroll
    for (int i = 0; i < 4; i++)
#pragma unroll
      for (int j = 0; j < 4; j++)
#pragma unroll
        for (int t = 0; t < 4; t++) {
          int row = bm * 128 + wm + i * 16 + quad * 4 + t;
          int col = bn * 128 + wn + j * 16 + m_in;
          C[(size_t)row * ldc + col] = acc[i][j][t];
        }
  }
}

// ---------------- softmax over k (row-wise on P[n][k]), single-exp ----------------
__global__ void softmax_rows(u16* __restrict__ P) {
  __shared__ __align__(16) u16 row[BANK_P];   // 19456 B
  __shared__ float red[8];
  const int n = blockIdx.x;                   // 0..N_TOK-1
  const int tid = threadIdx.x;
  u16* prow = P + (size_t)n * BANK_P;

  for (int k = tid; k < BANK_N; k += 256) row[k] = prow[k];
  __syncthreads();

  float m = -1e30f;
  for (int k = tid; k < BANK_N; k += 256) m = fmaxf(m, bf2f(row[k]));
#pragma unroll
  for (int o = 32; o; o >>= 1) m = fmaxf(m, __shfl_xor(m, o));
  if ((tid & 63) == 0) red[tid >> 6] = m;
  __syncthreads();
  m = fmaxf(fmaxf(red[0], red[1]), fmaxf(red[2], red[3]));

  float s = 0.f;
  for (int k = tid; k < BANK_N; k += 256) {
    float e = __expf(bf2f(row[k]) - m);
    row[k] = f2bf(e);                         // stash exp in place (bf16)
    s += e;
  }
#pragma unroll
  for (int o = 32; o; o >>= 1) s += __shfl_xor(s, o);
  if ((tid & 63) == 0) red[4 + (tid >> 6)] = s;
  __syncthreads();
  const float inv = 1.f / (red[4] + red[5] + red[6] + red[7]);

  for (int k = tid; k < BANK_N; k += 256)
    prow[k] = f2bf(bf2f(row[k]) * inv);
}

// ---------------- epilogue ----------------
__global__ void epilogue(const float* __restrict__ memC, const float* __restrict__ q_out,
                         float* __restrict__ out, int nParts) {
  int idx = blockIdx.x * 256 + threadIdx.x;
  if (idx >= OBJ_N * 1024 * N_TOK) return;
  int n = idx % N_TOK;
  int t = idx / N_TOK;
  int c = t & 1023;
  int o = t >> 10;
  const size_t ps = (size_t)M_PAD * LDCOL;
  float v;
  if (c < 512) {
    size_t off = (size_t)(o * 512 + c) * LDCOL + n;
    v = 0.f;
    for (int z = 0; z < nParts; z++) v += memC[z * ps + off];
  } else {
    size_t offm = (size_t)(1536 + o) * LDCOL + n;
    float mm = 0.f;
    for (int z = 0; z < nParts; z++) mm += memC[z * ps + offm];
    v = q_out[(size_t)(o * 512 + (c - 512)) * N_TOK + n] * mm;
  }
  out[idx] = v;
}

extern "C" void kernel_launch(void* const* d_in, const int* in_sizes, int n_in,
                              void* d_out, int out_size, void* d_ws, size_t ws_size,
                              hipStream_t stream) {
  const float* keys   = (const float*)d_in[0];
  const float* q_in   = (const float*)d_in[1];
  const float* q_out  = (const float*)d_in[2];
  const float* values = (const float*)d_in[3];
  const float* masks  = (const float*)d_in[4];
  float* out = (float*)d_out;

  char* ws = (char*)d_ws;
  size_t off = 0;
  auto alloc = [&](size_t bytes) -> void* {
    void* p = ws + off; off += (bytes + 255) & ~(size_t)255; return p;
  };
  u16* qT = (u16*)alloc((size_t)N_PAD * D_KEY * 2);
  u16* kT = (u16*)alloc((size_t)BANK_P * D_KEY * 2);
  u16* vm = (u16*)alloc((size_t)M_PAD * BANK_P * 2);
  u16* P  = (u16*)alloc((size_t)N_PAD * BANK_P * 2);

  int nParts = 8;
  while (nParts > 1 && off + (size_t)nParts * M_PAD * LDCOL * 4 > ws_size) nParts >>= 1;
  float* memC = (float*)alloc((size_t)nParts * M_PAD * LDCOL * 4);

  cast_qT<<<(N_PAD * D_KEY + 255) / 256, 256, 0, stream>>>(q_in, qT);
  transpose_keys<<<dim3(BANK_P / 64, D_KEY / 64), 256, 0, stream>>>(keys, kT);
  cast_vm<<<(M_PAD * (BANK_P / 4) + 255) / 256, 256, 0, stream>>>(values, masks, vm);

  // QK^T: St[n][k] = qT[n][:] . keysT[k][:]   (M=N_PAD, N=BANK_P, K=128)
  gemm_bt<true, false><<<dim3(BANK_P / 128, N_PAD / 128, 1), 256, 0, stream>>>(
      qT, kT, (void*)P, D_KEY, D_KEY, BANK_P, D_KEY, 0);

  softmax_rows<<<N_TOK, 256, 0, stream>>>(P);

  // mem: C[m][n] = vm[m][:] . P[n][:]   (M=M_PAD, N=N_PAD, K=BANK_P), split-K, swizzled
  int kChunk = BANK_P / nParts;
  gemm_bt<false, true><<<dim3(169 * nParts, 1, 1), 256, 0, stream>>>(
      vm, P, (void*)memC, BANK_P, BANK_P, LDCOL, kChunk, (size_t)M_PAD * LDCOL);

  epilogue<<<(OBJ_N * 1024 * N_TOK + 255) / 256, 256, 0, stream>>>(memC, q_out, out, nParts);
}

// Round 4
// 278.291 us; speedup vs baseline: 1.0525x; 1.0031x over previous
//
#include <hip/hip_runtime.h>
#include <hip/hip_bf16.h>

typedef unsigned short u16;

#define D_KEY   128
#define BANK_N  9720
#define BANK_P  9728   /* 76*128 */
#define N_TOK   1620
#define N_PAD   1664   /* 13*128 */
#define OBJ_N   3
#define M_ROWS  1539   /* 3*512 + 3 mask rows */
#define M_PAD   1664
#define LDCOL   1664
#define QK_SCALE 0.08838834764831845f

typedef __bf16 bf16x8 __attribute__((ext_vector_type(8)));
typedef float  f32x4  __attribute__((ext_vector_type(4)));
typedef unsigned int u32x4 __attribute__((ext_vector_type(4)));

__device__ __forceinline__ float bf2f(u16 u) {
  union { unsigned int i; float f; } v; v.i = ((unsigned int)u) << 16; return v.f;
}
__device__ __forceinline__ u16 f2bf(float f) {
  unsigned int x = __float_as_uint(f);
  unsigned int r = x + 0x7fffu + ((x >> 16) & 1u);  // RNE
  return (u16)(r >> 16);
}

__device__ __forceinline__ void load_lds16(const void* g, void* l) {
  __builtin_amdgcn_global_load_lds(
      (const __attribute__((address_space(1))) void*)g,
      (__attribute__((address_space(3))) void*)l, 16, 0, 0);
}

// ---------------- cast kernels ----------------
__global__ void cast_qT(const float* __restrict__ q, u16* __restrict__ qT,
                        float* __restrict__ lsum) {
  int idx = blockIdx.x * 256 + threadIdx.x;          // N_PAD*128
  if (idx < N_PAD) lsum[idx] = 0.f;                  // zero row-sum accumulator
  if (idx >= N_PAD * D_KEY) return;
  int n = idx >> 7, d = idx & 127;
  float v = (n < N_TOK) ? q[d * N_TOK + n] * QK_SCALE : 0.f;
  qT[idx] = f2bf(v);
}

// LDS-tiled transpose: keys[d][bank] (fp32) -> kT[bank][d] (bf16)
__global__ void transpose_keys(const float* __restrict__ keys, u16* __restrict__ kT) {
  __shared__ float t[64][65];
  const int bk = blockIdx.x * 64;
  const int bd = blockIdx.y * 64;
  const int tx = threadIdx.x & 63;
  const int ty = threadIdx.x >> 6;
#pragma unroll
  for (int i = 0; i < 64; i += 4) {
    int d = bd + ty + i;
    int k = bk + tx;
    t[ty + i][tx] = (k < BANK_N) ? keys[(size_t)d * BANK_N + k] : 0.f;
  }
  __syncthreads();
#pragma unroll
  for (int i = 0; i < 64; i += 4) {
    int r = ty + i;
    kT[(size_t)(bk + r) * D_KEY + bd + tx] = f2bf(t[tx][r]);
  }
}

__global__ void cast_vm(const float* __restrict__ values, const float* __restrict__ masks,
                        u16* __restrict__ vm) {
  const int NV = BANK_P / 4;
  int idx = blockIdx.x * 256 + threadIdx.x;
  if (idx >= M_PAD * NV) return;
  int m = idx / NV;
  int k4 = (idx - m * NV) * 4;
  float4 v = make_float4(0.f, 0.f, 0.f, 0.f);
  const float* src = nullptr;
  if (m < 1536)        src = values + (size_t)m * BANK_N;
  else if (m < M_ROWS) src = masks + (size_t)(m - 1536) * BANK_N;
  if (src) {
    if (k4 + 3 < BANK_N) v = *(const float4*)(src + k4);
    else {
      if (k4     < BANK_N) v.x = src[k4];
      if (k4 + 1 < BANK_N) v.y = src[k4 + 1];
      if (k4 + 2 < BANK_N) v.z = src[k4 + 2];
      if (k4 + 3 < BANK_N) v.w = src[k4 + 3];
    }
  }
  ushort4 o;
  o.x = f2bf(v.x); o.y = f2bf(v.y); o.z = f2bf(v.z); o.w = f2bf(v.w);
  *(ushort4*)(vm + (size_t)m * BANK_P + k4) = o;
}

// ---------------- GEMM: C[M][N] = A[M][K] * B[N][K]^T, bf16 in, u16 out ----------------
// 128x128 tile, BK=32, 256 threads, 4x4 MFMA subtiles/wave.
// EXPSUM: store exp(acc), accumulate row-sums into lsum (cols < ncols only).
// SWZ: 1D grid 169*nParts, grouped decode; C gets bz*cPartStride offset, NT stores.
template<bool EXPSUM, bool SWZ>
__global__ void gemm_bt(const u16* __restrict__ A, const u16* __restrict__ B,
                        u16* __restrict__ C, int lda, int ldb, int ldc,
                        int kChunk, size_t cPartStride, float* __restrict__ lsum, int ncols)
{
  __shared__ __align__(16) u16 sbuf[16384];   // 32 KB: As(8K)+Bs(8K) aliased by C-stage
  u16* As = sbuf;
  u16* Bs = sbuf + 4096;

  const int tid  = threadIdx.x;
  const int wave = tid >> 6;
  const int lane = tid & 63;

  int bn, bm, bz;
  if (SWZ) {
    int b = blockIdx.x;
    bz = b / 169;
    int rr = b - bz * 169;
    int gid = rr / 52;
    int rem = rr - gid * 52;
    int width = (gid < 3) ? 4 : 1;
    bm = rem / width;
    bn = gid * 4 + (rem - bm * width);
  } else {
    bn = blockIdx.x; bm = blockIdx.y; bz = 0;
  }

  const int kbeg = bz * kChunk;
  const int kend = kbeg + kChunk;

  const u16* Abase = A + (size_t)bm * 128 * lda;
  const u16* Bbase = B + (size_t)bn * 128 * ldb;

  const int r  = lane >> 2;
  const int c8 = (lane & 3) << 3;
  const int s0 = wave, s1 = wave + 4;

  f32x4 acc[4][4];
#pragma unroll
  for (int i = 0; i < 4; i++)
#pragma unroll
    for (int j = 0; j < 4; j++) acc[i][j] = (f32x4){0.f, 0.f, 0.f, 0.f};

  const int m_in = lane & 15;
  const int quad = lane >> 4;
  const int wm = (wave >> 1) * 64;
  const int wn = (wave & 1) * 64;

  for (int kt = kbeg; kt < kend; kt += 32) {
    load_lds16(Abase + (size_t)(s0 * 16 + r) * lda + kt + c8, &As[s0 * 512]);
    load_lds16(Abase + (size_t)(s1 * 16 + r) * lda + kt + c8, &As[s1 * 512]);
    load_lds16(Bbase + (size_t)(s0 * 16 + r) * ldb + kt + c8, &Bs[s0 * 512]);
    load_lds16(Bbase + (size_t)(s1 * 16 + r) * ldb + kt + c8, &Bs[s1 * 512]);
    __syncthreads();

    bf16x8 af[4], bfr[4];
#pragma unroll
    for (int i = 0; i < 4; i++)
      af[i] = *(const bf16x8*)&As[(wm + i * 16 + m_in) * 32 + quad * 8];
#pragma unroll
    for (int j = 0; j < 4; j++)
      bfr[j] = *(const bf16x8*)&Bs[(wn + j * 16 + m_in) * 32 + quad * 8];
#pragma unroll
    for (int i = 0; i < 4; i++)
#pragma unroll
      for (int j = 0; j < 4; j++)
        acc[i][j] = __builtin_amdgcn_mfma_f32_16x16x32_bf16(af[i], bfr[j], acc[i][j], 0, 0, 0);
    __syncthreads();
  }

  // ---- epilogue: (optional exp + row-sum), stage C tile in LDS, coalesced store ----
  float rs[4][4];
  if (EXPSUM)
#pragma unroll
    for (int i = 0; i < 4; i++)
#pragma unroll
      for (int t = 0; t < 4; t++) rs[i][t] = 0.f;

#pragma unroll
  for (int i = 0; i < 4; i++)
#pragma unroll
    for (int j = 0; j < 4; j++)
#pragma unroll
      for (int t = 0; t < 4; t++) {
        int row_l = wm + i * 16 + quad * 4 + t;   // D layout: col=lane&15, row=quad*4+t [m89]
        int col_l = wn + j * 16 + m_in;
        float v = acc[i][j][t];
        if (EXPSUM) {
          float e = __expf(v);
          if (bn * 128 + col_l < ncols) rs[i][t] += e;
          v = e;
        }
        sbuf[(row_l << 7) + col_l] = f2bf(v);
      }

  if (EXPSUM) {
#pragma unroll
    for (int i = 0; i < 4; i++)
#pragma unroll
      for (int t = 0; t < 4; t++) {
        float rv = rs[i][t];
        rv += __shfl_xor(rv, 1);
        rv += __shfl_xor(rv, 2);
        rv += __shfl_xor(rv, 4);
        rv += __shfl_xor(rv, 8);
        if ((lane & 15) == 0)
          atomicAdd(&lsum[bm * 128 + wm + i * 16 + quad * 4 + t], rv);
      }
  }
  __syncthreads();

  u16* Cg = C + (SWZ ? (size_t)bz * cPartStride : 0);
  for (int chunk = tid; chunk < 2048; chunk += 256) {
    int row = chunk >> 4;
    int cu  = (chunk & 15) << 3;
    u32x4 v = *(const u32x4*)&sbuf[(row << 7) + cu];
    u32x4* dst = (u32x4*)&Cg[(size_t)(bm * 128 + row) * ldc + bn * 128 + cu];
    if (EXPSUM) *dst = v;
    else        __builtin_nontemporal_store(v, dst);
  }
}

// ---------------- epilogue: sum bf16 partials, normalize by lsum, q_out product ----------------
__global__ void epilogue(const u16* __restrict__ memC, const float* __restrict__ q_out,
                         const float* __restrict__ lsum, float* __restrict__ out, int nParts) {
  int idx = blockIdx.x * 256 + threadIdx.x;
  if (idx >= OBJ_N * 1024 * N_TOK) return;
  int n = idx % N_TOK;
  int t = idx / N_TOK;
  int c = t & 1023;
  int o = t >> 10;
  const size_t ps = (size_t)M_PAD * LDCOL;
  const float invl = 1.f / lsum[n];
  float v;
  if (c < 512) {
    size_t off = (size_t)(o * 512 + c) * LDCOL + n;
    float s = 0.f;
    for (int z = 0; z < nParts; z++) s += bf2f(memC[z * ps + off]);
    v = s * invl;
  } else {
    size_t offm = (size_t)(1536 + o) * LDCOL + n;
    float mm = 0.f;
    for (int z = 0; z < nParts; z++) mm += bf2f(memC[z * ps + offm]);
    v = q_out[(size_t)(o * 512 + (c - 512)) * N_TOK + n] * mm * invl;
  }
  out[idx] = v;
}

extern "C" void kernel_launch(void* const* d_in, const int* in_sizes, int n_in,
                              void* d_out, int out_size, void* d_ws, size_t ws_size,
                              hipStream_t stream) {
  const float* keys   = (const float*)d_in[0];
  const float* q_in   = (const float*)d_in[1];
  const float* q_out  = (const float*)d_in[2];
  const float* values = (const float*)d_in[3];
  const float* masks  = (const float*)d_in[4];
  float* out = (float*)d_out;

  char* ws = (char*)d_ws;
  size_t off = 0;
  auto alloc = [&](size_t bytes) -> void* {
    void* p = ws + off; off += (bytes + 255) & ~(size_t)255; return p;
  };
  u16*   qT   = (u16*)alloc((size_t)N_PAD * D_KEY * 2);
  u16*   kT   = (u16*)alloc((size_t)BANK_P * D_KEY * 2);
  u16*   vm   = (u16*)alloc((size_t)M_PAD * BANK_P * 2);
  u16*   E    = (u16*)alloc((size_t)N_PAD * BANK_P * 2);
  float* lsum = (float*)alloc((size_t)N_PAD * 4);

  int nParts = 8;
  while (nParts > 1 && off + (size_t)nParts * M_PAD * LDCOL * 2 > ws_size) nParts >>= 1;
  u16* memC = (u16*)alloc((size_t)nParts * M_PAD * LDCOL * 2);

  cast_qT<<<(N_PAD * D_KEY + 255) / 256, 256, 0, stream>>>(q_in, qT, lsum);
  transpose_keys<<<dim3(BANK_P / 64, D_KEY / 64), 256, 0, stream>>>(keys, kT);
  cast_vm<<<(M_PAD * (BANK_P / 4) + 255) / 256, 256, 0, stream>>>(values, masks, vm);

  // QK^T + exp + row-sums: E[n][k] = exp(qT[n][:] . kT[k][:]), lsum[n] += ...
  gemm_bt<true, false><<<dim3(BANK_P / 128, N_PAD / 128, 1), 256, 0, stream>>>(
      qT, kT, E, D_KEY, D_KEY, BANK_P, D_KEY, 0, lsum, BANK_N);

  // PV: memC[z][m][n] = sum_{k in chunk z} vm[m][k] * E[n][k]  (bf16 partials, NT stores)
  int kChunk = BANK_P / nParts;
  gemm_bt<false, true><<<dim3(169 * nParts, 1, 1), 256, 0, stream>>>(
      vm, E, memC, BANK_P, BANK_P, LDCOL, kChunk, (size_t)M_PAD * LDCOL, nullptr, 0);

  epilogue<<<(OBJ_N * 1024 * N_TOK + 255) / 256, 256, 0, stream>>>(memC, q_out, lsum, out, nParts);
}